// Round 1
// baseline (179.977 us; speedup 1.0000x reference)
//
#include <hip/hip_runtime.h>
#include <math.h>

// DualClassify R9: coalesced global->LDS staging for phase 1.
//
// R8 read pred_candidates thread-per-traj at 400B stride / 16B granularity:
// rows are not 64B-sector aligned and 16 waves thrash the 32KB L1 between
// unroll windows -> ~1.6x HBM read amplification (est. ~170MB fetched vs
// 105MB mandatory). R9 stages each 64-traj segment (25.6KB) into LDS with
// __builtin_amdgcn_global_load_lds width=16: 1KB per instruction, perfectly
// coalesced, no VGPR round-trip. Thread-per-traj then consumes from LDS
// (8-way read bank conflict, ~0.37us/segment, hidden under the ~1.04us/segment
// HBM time). 4 waves/block x 25.6KB = 104KB static LDS; ~100KB of async
// staging in flight per CU >> the ~9KB needed to cover HBM latency.
//
// Fast path is specialized to T=50 (bench shape); generic T falls back to the
// proven R8 kernel. Same single-dispatch structure: block-per-sample, one
// device-scope atomicAdd(out) per block, d_out's 0xAA poison (~-3e-13) absorbed.

#define LANE_WEIGHT 1.0f
#define TEMP_INV    10.0f   // 1 / 0.1

#define TT     50           // fast-path T
#define FPT    25           // float4s per traj = TT*2/4
#define NWAVES 4            // waves per block in fast path

typedef float v4f __attribute__((ext_vector_type(4)));

typedef __attribute__((address_space(1))) const unsigned int gu32;
typedef __attribute__((address_space(3))) unsigned int       lu32;

__device__ __forceinline__ void stage16(const float* g, v4f* l)
{
    // dest is wave-uniform base; HW writes lane i's 16B to l + i*16
    __builtin_amdgcn_global_load_lds((gu32*)g, (lu32*)l, 16, 0, 0);
}

// ---------------------------------------------------------------------------
// Fast path: T == 50, K <= 64 trajs/lane, <= 64 lanes/sample.
__global__ __launch_bounds__(256) void dual_classify_fast(
    const float* __restrict__ pred_candidates,  // [NT, 50, 2]
    const float* __restrict__ pred_gt,          // [B, 50, 2]
    const float* __restrict__ traj_scores,      // [NT, 1]
    const float* __restrict__ scales,           // [B]
    const float* __restrict__ lane_scores,      // [NL]
    const int*   __restrict__ cls_oracle,       // [NL]
    const int*   __restrict__ cls_se,           // [B, 2]
    const int*   __restrict__ trajs_se,         // [NL, 2]
    float*       __restrict__ out,              // [1] (0xAA-poisoned ~ -3e-13)
    int B)
{
    __shared__ v4f   buf[NWAVES][64 * FPT];     // 4 x 25.6 KB staging buffers
    __shared__ v4f   s_gt[FPT];                 // this sample's GT row (400 B)
    __shared__ float s_ce[64];                  // traj-CE per lane

    const int sample = blockIdx.x;
    const int wid    = threadIdx.x >> 6;
    const int lid    = threadIdx.x & 63;

    const int cs = cls_se[2 * sample];
    const int nl = cls_se[2 * sample + 1] - cs;   // lanes in sample (<=64)

    if (threadIdx.x < FPT)
        s_gt[threadIdx.x] =
            ((const v4f*)(pred_gt + (size_t)sample * (2 * TT)))[threadIdx.x];
    const float inv_scale = 1.0f / scales[sample];
    __syncthreads();   // s_gt visible to all waves

    // ---- Phase 1: wave-per-lane, LDS-staged ----
    for (int li = wid; li < nl; li += NWAVES) {
        const int lane = cs + li;
        const int t0   = trajs_se[2 * lane];
        const int Kl   = trajs_se[2 * lane + 1] - t0;   // trajs (<=64)
        const int NF   = Kl * FPT;                      // float4s in segment

        // coalesced async stage: call r moves f4s [r*64, r*64+64) of the
        // segment into buf[wid] linearly (1KB per call)
        const float* gbase  = pred_candidates + (size_t)t0 * (2 * TT);
        const int    ncalls = (NF + 63) >> 6;           // 25 for Kl=64
        for (int r = 0; r < ncalls; ++r) {
            const int idx = (r << 6) + lid;
            if (idx < NF)
                stage16(gbase + (size_t)idx * 4, &buf[wid][r << 6]);
        }
        asm volatile("s_waitcnt vmcnt(0)" ::: "memory");

        // thread-per-traj ADE from LDS; s_gt[j] is a uniform broadcast
        const bool valid = (lid < Kl);
        float sum = 0.0f;
        {
            const v4f* tp = &buf[wid][lid * FPT];
            #pragma unroll 5
            for (int j = 0; j < FPT; ++j) {
                v4f c = tp[j];
                v4f g = s_gt[j];
                float dx0 = c.x - g.x, dy0 = c.y - g.y;
                float dx1 = c.z - g.z, dy1 = c.w - g.w;
                sum += sqrtf(dx0 * dx0 + dy0 * dy0 + 1e-12f)
                     + sqrtf(dx1 * dx1 + dy1 * dy1 + 1e-12f);
            }
        }

        // dual softmax over the wave's K trajs (R8's proven body)
        float sc = valid ? (-(sum / (float)TT) * inv_scale * TEMP_INV)
                         : -INFINITY;
        float m = sc;
        for (int off = 32; off; off >>= 1) m = fmaxf(m, __shfl_xor(m, off));
        float e = valid ? expf(sc - m) : 0.0f;
        float Z = e;
        for (int off = 32; off; off >>= 1) Z += __shfl_xor(Z, off);
        float target = e / Z;

        const int traj = t0 + (valid ? lid : (Kl > 0 ? Kl - 1 : 0));
        float tsc = valid ? traj_scores[traj] : -INFINITY;
        float m2 = tsc;
        for (int off = 32; off; off >>= 1) m2 = fmaxf(m2, __shfl_xor(m2, off));
        float e2 = valid ? expf(tsc - m2) : 0.0f;
        float Z2 = e2;
        for (int off = 32; off; off >>= 1) Z2 += __shfl_xor(Z2, off);
        float logp = (tsc - m2) - logf(Z2);

        float ce = valid ? (-target * logp) : 0.0f;
        for (int off = 32; off; off >>= 1) ce += __shfl_xor(ce, off);
        if (lid == 0) s_ce[li] = ce;
    }
    __syncthreads();

    // ---- Phase 2 (wave 0): lane-level softmax + oracle combine ----
    if (wid == 0) {
        const bool v = (lid < nl);
        const int  l = cs + (v ? lid : 0);

        float sc = v ? lane_scores[l] : -INFINITY;
        float m = sc;
        for (int off = 32; off; off >>= 1) m = fmaxf(m, __shfl_xor(m, off));
        float e = v ? expf(sc - m) : 0.0f;
        float Z = e;
        for (int off = 32; off; off >>= 1) Z += __shfl_xor(Z, off);
        const float lse = m + logf(Z);

        const bool o = v && (cls_oracle[l] != 0);
        float cnt = o ? 1.0f : 0.0f;
        float ll  = o ? -(sc - lse) : 0.0f;
        float tl  = o ? s_ce[lid]   : 0.0f;
        for (int off = 32; off; off >>= 1) {
            cnt += __shfl_xor(cnt, off);
            ll  += __shfl_xor(ll,  off);
            tl  += __shfl_xor(tl,  off);
        }
        if (lid == 0) {
            const float sample_loss = (ll * LANE_WEIGHT + tl) / cnt;
            atomicAdd(out, sample_loss / (float)B);
        }
    }
}

// ---------------------------------------------------------------------------
// Generic fallback (R8 kernel, verbatim): any even/odd T, K<=64, lanes<=64.
__global__ __launch_bounds__(1024) void dual_classify_sample(
    const float* __restrict__ pred_candidates,
    const float* __restrict__ pred_gt,
    const float* __restrict__ traj_scores,
    const float* __restrict__ scales,
    const float* __restrict__ lane_scores,
    const int*   __restrict__ cls_oracle,
    const int*   __restrict__ cls_se,
    const int*   __restrict__ trajs_se,
    float*       __restrict__ out,
    int B, int T)
{
    const int sample = blockIdx.x;
    const int wid    = threadIdx.x >> 6;
    const int lid    = threadIdx.x & 63;
    const int nwaves = blockDim.x >> 6;

    const int cs   = cls_se[2 * sample];
    const int cend = cls_se[2 * sample + 1];
    const int nl   = cend - cs;

    __shared__ float s_ce[64];

    const int nf4 = (T * 2) / 4;
    const v4f* __restrict__ gp =
        (const v4f*)(pred_gt + (size_t)sample * (T * 2));
    const float inv_scale = 1.0f / scales[sample];

    for (int li = wid; li < nl; li += nwaves) {
        const int lane = cs + li;
        const int t0 = trajs_se[2 * lane];
        const int Kl = trajs_se[2 * lane + 1] - t0;

        const bool valid = (lid < Kl);
        const int  traj  = t0 + (valid ? lid : (Kl > 0 ? Kl - 1 : 0));
        const v4f* __restrict__ tp =
            (const v4f*)(pred_candidates + (size_t)traj * (T * 2));

        float sum = 0.0f;
        #pragma unroll 5
        for (int r = 0; r < nf4; ++r) {
            v4f c = tp[r];
            v4f g = gp[r];
            float dx0 = c.x - g.x, dy0 = c.y - g.y;
            float dx1 = c.z - g.z, dy1 = c.w - g.w;
            sum += sqrtf(dx0 * dx0 + dy0 * dy0 + 1e-12f)
                 + sqrtf(dx1 * dx1 + dy1 * dy1 + 1e-12f);
        }
        if ((T & 1) != 0) {
            const float2* tp2 = (const float2*)tp;
            const float2* gp2 = (const float2*)gp;
            float2 c = tp2[2 * nf4], g = gp2[2 * nf4];
            float dx = c.x - g.x, dy = c.y - g.y;
            sum += sqrtf(dx * dx + dy * dy + 1e-12f);
        }

        float sc = valid ? (-(sum / (float)T) * inv_scale * TEMP_INV)
                         : -INFINITY;
        float m = sc;
        for (int off = 32; off; off >>= 1) m = fmaxf(m, __shfl_xor(m, off));
        float e = valid ? expf(sc - m) : 0.0f;
        float Z = e;
        for (int off = 32; off; off >>= 1) Z += __shfl_xor(Z, off);
        float target = e / Z;

        float tsc = valid ? traj_scores[traj] : -INFINITY;
        float m2 = tsc;
        for (int off = 32; off; off >>= 1) m2 = fmaxf(m2, __shfl_xor(m2, off));
        float e2 = valid ? expf(tsc - m2) : 0.0f;
        float Z2 = e2;
        for (int off = 32; off; off >>= 1) Z2 += __shfl_xor(Z2, off);
        float logp = (tsc - m2) - logf(Z2);

        float ce = valid ? (-target * logp) : 0.0f;
        for (int off = 32; off; off >>= 1) ce += __shfl_xor(ce, off);
        if (lid == 0) s_ce[li] = ce;
    }
    __syncthreads();

    if (wid == 0) {
        const bool v = (lid < nl);
        const int  l = cs + (v ? lid : 0);

        float sc = v ? lane_scores[l] : -INFINITY;
        float m = sc;
        for (int off = 32; off; off >>= 1) m = fmaxf(m, __shfl_xor(m, off));
        float e = v ? expf(sc - m) : 0.0f;
        float Z = e;
        for (int off = 32; off; off >>= 1) Z += __shfl_xor(Z, off);
        const float lse = m + logf(Z);

        const bool o = v && (cls_oracle[l] != 0);
        float cnt = o ? 1.0f : 0.0f;
        float ll  = o ? -(sc - lse) : 0.0f;
        float tl  = o ? s_ce[lid]   : 0.0f;
        for (int off = 32; off; off >>= 1) {
            cnt += __shfl_xor(cnt, off);
            ll  += __shfl_xor(ll,  off);
            tl  += __shfl_xor(tl,  off);
        }
        if (lid == 0) {
            const float sample_loss = (ll * LANE_WEIGHT + tl) / cnt;
            atomicAdd(out, sample_loss / (float)B);
        }
    }
}

// ---------------------------------------------------------------------------
extern "C" void kernel_launch(void* const* d_in, const int* in_sizes, int n_in,
                              void* d_out, int out_size, void* d_ws, size_t ws_size,
                              hipStream_t stream)
{
    const float* lane_scores     = (const float*)d_in[0];
    const float* traj_scores     = (const float*)d_in[1];
    const float* pred_candidates = (const float*)d_in[2];
    const float* pred_gt         = (const float*)d_in[3];
    const float* scales          = (const float*)d_in[4];
    const int*   cls_oracle      = (const int*)d_in[5];
    const int*   cls_se          = (const int*)d_in[6];
    const int*   trajs_se        = (const int*)d_in[7];

    const int NT = in_sizes[1];
    const int B  = in_sizes[6] / 2;
    const int T  = in_sizes[2] / (NT * 2);   // 50

    float* out = (float*)d_out;

    if (T == TT) {
        dual_classify_fast<<<B, NWAVES * 64, 0, stream>>>(
            pred_candidates, pred_gt, traj_scores, scales, lane_scores,
            cls_oracle, cls_se, trajs_se, out, B);
    } else {
        dual_classify_sample<<<B, 1024, 0, stream>>>(
            pred_candidates, pred_gt, traj_scores, scales, lane_scores,
            cls_oracle, cls_se, trajs_se, out, B, T);
    }
}

// Round 2
// 179.355 us; speedup vs baseline: 1.0035x; 1.0035x over previous
//
#include <hip/hip_runtime.h>
#include <math.h>

// DualClassify R10: full-row register loads, no traj LDS staging.
//
// R8's defect was NOT the thread-per-traj layout per se — it was the
// `#pragma unroll 5` window: each lane touched 80B of its 400B row, then
// 15 other waves thrashed the 32KB L1 before the next window, re-fetching
// the shared boundary sectors (~1.6x HBM amplification). R9's LDS staging
// fixed the fetch but serialized stage->vmcnt(0)->compute at 1 wave/SIMD
// (104KB LDS -> 1 block/CU) and added a ~32-way LDS read conflict
// (lane stride 1600B -> 2 banks), netting ~zero.
//
// R10: each lane issues its ENTIRE 400B row as 25 back-to-back
// global_load_dwordx4 (fully unrolled into registers, sched_barrier(0)
// between load phase and consume phase). All same-sector requests are in
// flight together -> L1 MSHR merge; stragglers hit the XCD L2 (streamed
// lines persist for the us-scale window). HBM fetch ~= the mandatory
// 105MB. 512-thread blocks (8 waves, 2/SIMD) give TLP to hide the ~900cyc
// HBM latency; ~130 VGPR live fits the 256 cap at 8 waves/CU.
//
// Same single-dispatch structure: block-per-sample, one device-scope
// atomicAdd(out) per block, d_out's 0xAA poison (~-3e-13) absorbed.

#define LANE_WEIGHT 1.0f
#define TEMP_INV    10.0f   // 1 / 0.1

#define TT     50           // fast-path T
#define FPT    25           // float4s per traj = TT*2/4
#define NWAVES 8            // waves per block in fast path

typedef float v4f __attribute__((ext_vector_type(4)));

// ---------------------------------------------------------------------------
// Fast path: T == 50, K <= 64 trajs/lane, <= 64 lanes/sample.
__global__ __launch_bounds__(512) void dual_classify_fast(
    const float* __restrict__ pred_candidates,  // [NT, 50, 2]
    const float* __restrict__ pred_gt,          // [B, 50, 2]
    const float* __restrict__ traj_scores,      // [NT, 1]
    const float* __restrict__ scales,           // [B]
    const float* __restrict__ lane_scores,      // [NL]
    const int*   __restrict__ cls_oracle,       // [NL]
    const int*   __restrict__ cls_se,           // [B, 2]
    const int*   __restrict__ trajs_se,         // [NL, 2]
    float*       __restrict__ out,              // [1] (0xAA-poisoned ~ -3e-13)
    int B)
{
    __shared__ v4f   s_gt[FPT];                 // this sample's GT row (400 B)
    __shared__ float s_ce[64];                  // traj-CE per lane

    const int sample = blockIdx.x;
    const int wid    = threadIdx.x >> 6;        // 0..7
    const int lid    = threadIdx.x & 63;

    const int cs = cls_se[2 * sample];
    const int nl = cls_se[2 * sample + 1] - cs;   // lanes in sample (<=64)

    if (threadIdx.x < FPT)
        s_gt[threadIdx.x] =
            ((const v4f*)(pred_gt + (size_t)sample * (2 * TT)))[threadIdx.x];
    const float inv_scale = 1.0f / scales[sample];
    __syncthreads();   // s_gt visible to all waves

    // ---- Phase 1: wave-per-lane, thread-per-traj, full-row reg loads ----
    for (int li = wid; li < nl; li += NWAVES) {
        const int lane = cs + li;
        const int t0   = trajs_se[2 * lane];
        const int Kl   = trajs_se[2 * lane + 1] - t0;   // trajs (<=64)

        const bool valid = (lid < Kl);
        const int  traj  = t0 + (valid ? lid : (Kl > 0 ? Kl - 1 : 0));
        const v4f* __restrict__ tp =
            (const v4f*)(pred_candidates + (size_t)traj * (2 * TT));

        // load the whole 400B row: 25 dwordx4, all in flight simultaneously
        v4f c[FPT];
        #pragma unroll
        for (int j = 0; j < FPT; ++j) c[j] = tp[j];
        __builtin_amdgcn_sched_barrier(0);   // keep loads clustered ahead

        float sum = 0.0f;
        #pragma unroll
        for (int j = 0; j < FPT; ++j) {
            v4f g = s_gt[j];                 // uniform LDS broadcast
            float dx0 = c[j].x - g.x, dy0 = c[j].y - g.y;
            float dx1 = c[j].z - g.z, dy1 = c[j].w - g.w;
            sum += sqrtf(dx0 * dx0 + dy0 * dy0 + 1e-12f)
                 + sqrtf(dx1 * dx1 + dy1 * dy1 + 1e-12f);
        }

        // dual softmax over the wave's K trajs (R8's proven body)
        float sc = valid ? (-(sum / (float)TT) * inv_scale * TEMP_INV)
                         : -INFINITY;
        float m = sc;
        for (int off = 32; off; off >>= 1) m = fmaxf(m, __shfl_xor(m, off));
        float e = valid ? expf(sc - m) : 0.0f;
        float Z = e;
        for (int off = 32; off; off >>= 1) Z += __shfl_xor(Z, off);
        float target = e / Z;

        float tsc = valid ? traj_scores[traj] : -INFINITY;
        float m2 = tsc;
        for (int off = 32; off; off >>= 1) m2 = fmaxf(m2, __shfl_xor(m2, off));
        float e2 = valid ? expf(tsc - m2) : 0.0f;
        float Z2 = e2;
        for (int off = 32; off; off >>= 1) Z2 += __shfl_xor(Z2, off);
        float logp = (tsc - m2) - logf(Z2);

        float ce = valid ? (-target * logp) : 0.0f;
        for (int off = 32; off; off >>= 1) ce += __shfl_xor(ce, off);
        if (lid == 0) s_ce[li] = ce;
    }
    __syncthreads();

    // ---- Phase 2 (wave 0): lane-level softmax + oracle combine ----
    if (wid == 0) {
        const bool v = (lid < nl);
        const int  l = cs + (v ? lid : 0);

        float sc = v ? lane_scores[l] : -INFINITY;
        float m = sc;
        for (int off = 32; off; off >>= 1) m = fmaxf(m, __shfl_xor(m, off));
        float e = v ? expf(sc - m) : 0.0f;
        float Z = e;
        for (int off = 32; off; off >>= 1) Z += __shfl_xor(Z, off);
        const float lse = m + logf(Z);

        const bool o = v && (cls_oracle[l] != 0);
        float cnt = o ? 1.0f : 0.0f;
        float ll  = o ? -(sc - lse) : 0.0f;
        float tl  = o ? s_ce[lid]   : 0.0f;
        for (int off = 32; off; off >>= 1) {
            cnt += __shfl_xor(cnt, off);
            ll  += __shfl_xor(ll,  off);
            tl  += __shfl_xor(tl,  off);
        }
        if (lid == 0) {
            const float sample_loss = (ll * LANE_WEIGHT + tl) / cnt;
            atomicAdd(out, sample_loss / (float)B);
        }
    }
}

// ---------------------------------------------------------------------------
// Generic fallback (R8 kernel, verbatim): any even/odd T, K<=64, lanes<=64.
__global__ __launch_bounds__(1024) void dual_classify_sample(
    const float* __restrict__ pred_candidates,
    const float* __restrict__ pred_gt,
    const float* __restrict__ traj_scores,
    const float* __restrict__ scales,
    const float* __restrict__ lane_scores,
    const int*   __restrict__ cls_oracle,
    const int*   __restrict__ cls_se,
    const int*   __restrict__ trajs_se,
    float*       __restrict__ out,
    int B, int T)
{
    const int sample = blockIdx.x;
    const int wid    = threadIdx.x >> 6;
    const int lid    = threadIdx.x & 63;
    const int nwaves = blockDim.x >> 6;

    const int cs   = cls_se[2 * sample];
    const int cend = cls_se[2 * sample + 1];
    const int nl   = cend - cs;

    __shared__ float s_ce[64];

    const int nf4 = (T * 2) / 4;
    const v4f* __restrict__ gp =
        (const v4f*)(pred_gt + (size_t)sample * (T * 2));
    const float inv_scale = 1.0f / scales[sample];

    for (int li = wid; li < nl; li += nwaves) {
        const int lane = cs + li;
        const int t0 = trajs_se[2 * lane];
        const int Kl = trajs_se[2 * lane + 1] - t0;

        const bool valid = (lid < Kl);
        const int  traj  = t0 + (valid ? lid : (Kl > 0 ? Kl - 1 : 0));
        const v4f* __restrict__ tp =
            (const v4f*)(pred_candidates + (size_t)traj * (T * 2));

        float sum = 0.0f;
        #pragma unroll 5
        for (int r = 0; r < nf4; ++r) {
            v4f c = tp[r];
            v4f g = gp[r];
            float dx0 = c.x - g.x, dy0 = c.y - g.y;
            float dx1 = c.z - g.z, dy1 = c.w - g.w;
            sum += sqrtf(dx0 * dx0 + dy0 * dy0 + 1e-12f)
                 + sqrtf(dx1 * dx1 + dy1 * dy1 + 1e-12f);
        }
        if ((T & 1) != 0) {
            const float2* tp2 = (const float2*)tp;
            const float2* gp2 = (const float2*)gp;
            float2 c = tp2[2 * nf4], g = gp2[2 * nf4];
            float dx = c.x - g.x, dy = c.y - g.y;
            sum += sqrtf(dx * dx + dy * dy + 1e-12f);
        }

        float sc = valid ? (-(sum / (float)T) * inv_scale * TEMP_INV)
                         : -INFINITY;
        float m = sc;
        for (int off = 32; off; off >>= 1) m = fmaxf(m, __shfl_xor(m, off));
        float e = valid ? expf(sc - m) : 0.0f;
        float Z = e;
        for (int off = 32; off; off >>= 1) Z += __shfl_xor(Z, off);
        float target = e / Z;

        float tsc = valid ? traj_scores[traj] : -INFINITY;
        float m2 = tsc;
        for (int off = 32; off; off >>= 1) m2 = fmaxf(m2, __shfl_xor(m2, off));
        float e2 = valid ? expf(tsc - m2) : 0.0f;
        float Z2 = e2;
        for (int off = 32; off; off >>= 1) Z2 += __shfl_xor(Z2, off);
        float logp = (tsc - m2) - logf(Z2);

        float ce = valid ? (-target * logp) : 0.0f;
        for (int off = 32; off; off >>= 1) ce += __shfl_xor(ce, off);
        if (lid == 0) s_ce[li] = ce;
    }
    __syncthreads();

    if (wid == 0) {
        const bool v = (lid < nl);
        const int  l = cs + (v ? lid : 0);

        float sc = v ? lane_scores[l] : -INFINITY;
        float m = sc;
        for (int off = 32; off; off >>= 1) m = fmaxf(m, __shfl_xor(m, off));
        float e = v ? expf(sc - m) : 0.0f;
        float Z = e;
        for (int off = 32; off; off >>= 1) Z += __shfl_xor(Z, off);
        const float lse = m + logf(Z);

        const bool o = v && (cls_oracle[l] != 0);
        float cnt = o ? 1.0f : 0.0f;
        float ll  = o ? -(sc - lse) : 0.0f;
        float tl  = o ? s_ce[lid]   : 0.0f;
        for (int off = 32; off; off >>= 1) {
            cnt += __shfl_xor(cnt, off);
            ll  += __shfl_xor(ll,  off);
            tl  += __shfl_xor(tl,  off);
        }
        if (lid == 0) {
            const float sample_loss = (ll * LANE_WEIGHT + tl) / cnt;
            atomicAdd(out, sample_loss / (float)B);
        }
    }
}

// ---------------------------------------------------------------------------
extern "C" void kernel_launch(void* const* d_in, const int* in_sizes, int n_in,
                              void* d_out, int out_size, void* d_ws, size_t ws_size,
                              hipStream_t stream)
{
    const float* lane_scores     = (const float*)d_in[0];
    const float* traj_scores     = (const float*)d_in[1];
    const float* pred_candidates = (const float*)d_in[2];
    const float* pred_gt         = (const float*)d_in[3];
    const float* scales          = (const float*)d_in[4];
    const int*   cls_oracle      = (const int*)d_in[5];
    const int*   cls_se          = (const int*)d_in[6];
    const int*   trajs_se        = (const int*)d_in[7];

    const int NT = in_sizes[1];
    const int B  = in_sizes[6] / 2;
    const int T  = in_sizes[2] / (NT * 2);   // 50

    float* out = (float*)d_out;

    if (T == TT) {
        dual_classify_fast<<<B, NWAVES * 64, 0, stream>>>(
            pred_candidates, pred_gt, traj_scores, scales, lane_scores,
            cls_oracle, cls_se, trajs_se, out, B);
    } else {
        dual_classify_sample<<<B, 1024, 0, stream>>>(
            pred_candidates, pred_gt, traj_scores, scales, lane_scores,
            cls_oracle, cls_se, trajs_se, out, B, T);
    }
}